// Round 1
// baseline (1366.612 us; speedup 1.0000x reference)
//
#include <hip/hip_runtime.h>

// RecurrentSNN: B=256, T=1024, F=64, H=512, O=64
// out = concat(mem_rec [B,T,O], spk_rec [B,T,O]) as f32.
//
// One persistent block per batch element b (grid=256 == #CUs).
// 512 threads = 8 waves = 2 waves/SIMD. Weights pinned in VGPRs:
//   thread j: W_in[j][0..63]  (layer-1 row h=j)
//             W_out[j&63][(j>>6)*64 .. +63] (layer-2 slice)
// Per time step:
//   stage x_t (64 f32) -> LDS, broadcast-read (uniform addr, conflict-free)
//   layer1: 64 fma/thread -> mem1 update (register state) -> spike -> LDS
//   layer2: 64 fma/thread partials -> LDS -> wave0 8-way reduce,
//           mem_out update, coalesced 256B stores of mem/spk.
// All f32 (no dtype downcast: spikes are 0/1, threshold crossings are
// sensitive; bf16 anywhere would flip spikes).

namespace {
constexpr int kB = 256;
constexpr int kT = 1024;
constexpr int kF = 64;
constexpr int kH = 512;
constexpr int kO = 64;
constexpr float kBeta = 0.9f;
constexpr float kThresh = 1.0f;
constexpr int kThreads = 512;
}  // namespace

__global__ __launch_bounds__(kThreads, 2)
void snn_fused_kernel(const float* __restrict__ x,
                      const float* __restrict__ W_in,
                      const float* __restrict__ b_in,
                      const float* __restrict__ W_out,
                      const float* __restrict__ b_out,
                      float* __restrict__ out) {
  const int b = blockIdx.x;
  const int j = threadIdx.x;
  const int o = j & 63;   // output index this thread contributes to (layer 2)
  const int s = j >> 6;   // which 64-wide h-slice this thread sums (== wave id)

  __shared__ float xs[kF];        // staged x_t
  __shared__ float spk_lds[kH];   // layer-1 spikes
  __shared__ float red[kH];       // layer-2 partials, red[s*64+o]

  // ---- pin weights in registers (one-time; W_in/W_out are L2-resident) ----
  float win[kF];
#pragma unroll
  for (int q = 0; q < kF / 4; ++q) {
    const float4 v = *reinterpret_cast<const float4*>(W_in + j * kF + q * 4);
    win[q * 4 + 0] = v.x; win[q * 4 + 1] = v.y;
    win[q * 4 + 2] = v.z; win[q * 4 + 3] = v.w;
  }
  float wout[64];
#pragma unroll
  for (int q = 0; q < 16; ++q) {
    const float4 v =
        *reinterpret_cast<const float4*>(W_out + o * kH + s * 64 + q * 4);
    wout[q * 4 + 0] = v.x; wout[q * 4 + 1] = v.y;
    wout[q * 4 + 2] = v.z; wout[q * 4 + 3] = v.w;
  }
  const float bin_j = b_in[j];
  const float bout_o = b_out[o];

  // ---- carried state (registers only) ----
  float mem1 = 0.0f, rst1 = 0.0f;   // rst1 == spike_{t-1} == (mem1_prev > 1)
  float memo = 0.0f, rsto = 0.0f;

  const float4* xrow =
      reinterpret_cast<const float4*>(x + (size_t)b * kT * kF);
  float* out_mem = out + (size_t)b * kT * kO;
  float* out_spk = out_mem + (size_t)kB * kT * kO;

  for (int t = 0; t < kT; ++t) {
    // stage x_t: 16 lanes x float4 = 64 f32
    if (j < kF / 4) {
      reinterpret_cast<float4*>(xs)[j] = xrow[t * (kF / 4) + j];
    }
    __syncthreads();

    // ---- layer 1: cur1[h=j] = b_in[j] + sum_f x_t[f] * W_in[j][f] ----
    float c0 = bin_j, c1 = 0.0f, c2 = 0.0f, c3 = 0.0f;
#pragma unroll
    for (int q = 0; q < 16; ++q) {
      const float4 xv = reinterpret_cast<const float4*>(xs)[q];  // broadcast
      c0 = fmaf(xv.x, win[q * 4 + 0], c0);
      c1 = fmaf(xv.y, win[q * 4 + 1], c1);
      c2 = fmaf(xv.z, win[q * 4 + 2], c2);
      c3 = fmaf(xv.w, win[q * 4 + 3], c3);
    }
    const float cur1 = (c0 + c1) + (c2 + c3);
    mem1 = kBeta * mem1 + cur1 - rst1;          // reset-by-subtract
    const float spk = (mem1 > kThresh) ? 1.0f : 0.0f;
    rst1 = spk;                                  // next step's reset
    spk_lds[j] = spk;
    __syncthreads();

    // ---- layer 2 partial: sum over h in [s*64, s*64+64) for output o ----
    float a0 = 0.0f, a1 = 0.0f, a2 = 0.0f, a3 = 0.0f;
    const float4* sp = reinterpret_cast<const float4*>(spk_lds + s * 64);
#pragma unroll
    for (int q = 0; q < 16; ++q) {
      const float4 sv = sp[q];  // uniform addr per wave -> broadcast
      a0 = fmaf(sv.x, wout[q * 4 + 0], a0);
      a1 = fmaf(sv.y, wout[q * 4 + 1], a1);
      a2 = fmaf(sv.z, wout[q * 4 + 2], a2);
      a3 = fmaf(sv.w, wout[q * 4 + 3], a3);
    }
    red[j] = (a0 + a1) + (a2 + a3);
    __syncthreads();

    // ---- wave 0: reduce 8 slices, update mem_out, store outputs ----
    if (j < kO) {
      float co = bout_o;
#pragma unroll
      for (int s2 = 0; s2 < kH / 64; ++s2) co += red[s2 * 64 + j];
      memo = kBeta * memo + co - rsto;
      const float so = (memo > kThresh) ? 1.0f : 0.0f;
      rsto = so;
      out_mem[t * kO + j] = memo;   // 64 consecutive f32 = coalesced 256B
      out_spk[t * kO + j] = so;
    }
    // xs(t+1) is written by wave 0 only after it passes this iteration's
    // last barrier; all other waves wait at the top-of-loop barrier, so
    // no wave can still be reading xs(t)/red(t) when they are overwritten.
  }
}

extern "C" void kernel_launch(void* const* d_in, const int* in_sizes, int n_in,
                              void* d_out, int out_size, void* d_ws,
                              size_t ws_size, hipStream_t stream) {
  const float* x = (const float*)d_in[0];
  const float* W_in = (const float*)d_in[1];
  const float* b_in = (const float*)d_in[2];
  const float* W_out = (const float*)d_in[3];
  const float* b_out = (const float*)d_in[4];
  float* out = (float*)d_out;

  hipLaunchKernelGGL(snn_fused_kernel, dim3(kB), dim3(kThreads), 0, stream,
                     x, W_in, b_in, W_out, b_out, out);
}

// Round 2
// 1168.793 us; speedup vs baseline: 1.1693x; 1.1693x over previous
//
#include <hip/hip_runtime.h>

// RecurrentSNN: B=256, T=1024, F=64, H=512, O=64
// out = concat(mem_rec [B,T,O], spk_rec [B,T,O]) f32.
//
// One block per batch element (grid=256=CUs), 512 threads = 8 waves.
// thread j: owns W_in row h=j (64 VGPR) and W_out[o=j&63][s*64..s*64+63]
// (64 VGPR), s = j>>6 = wave id.
//
// Per step (vs round-1: LDS-broadcast-bound at ~2500 cy/CU/step):
//  - x_t broadcast  -> 4x s_load_dwordx16 into SGPRs (scalar cache, no LDS)
//  - spike exchange -> __ballot: wave s needs ONLY its own wave's spikes
//    (h-slice == wave slice). SALU bit->1.0f/0.0f, co-issues with VALU.
//  - LDS only for the 8x64 cross-wave partial reduce, double-buffered,
//    ONE raw barrier/step (lgkmcnt(0)+s_barrier, no vmcnt drain).
// Arithmetic is bit-identical to the round-1 passing kernel (same fma
// order, same values) -- absmax must stay ~0.044.

typedef __attribute__((ext_vector_type(16))) float f32x16;

namespace {
constexpr int kB = 256;
constexpr int kT = 1024;
constexpr int kF = 64;
constexpr int kH = 512;
constexpr int kO = 64;
constexpr float kBeta = 0.9f;
constexpr float kThresh = 1.0f;
constexpr int kThreads = 512;
}  // namespace

// x element i (0..63) from the four SGPR vectors (i is unroll-constant).
#define XV(i) ((i) < 16 ? sx0[(i)] : (i) < 32 ? sx1[(i)-16] \
             : (i) < 48 ? sx2[(i)-32] : sx3[(i)-48])
// spike float for in-slice index k (0..63) from this wave's ballot mask.
#define BITF(k) ((((k) < 32 ? (mlo >> (k)) : (mhi >> ((k)-32))) & 1u) \
                 ? 1.0f : 0.0f)

__global__ __launch_bounds__(kThreads, 2)
void snn_fused2(const float* __restrict__ x,
                const float* __restrict__ W_in,
                const float* __restrict__ b_in,
                const float* __restrict__ W_out,
                const float* __restrict__ b_out,
                float* __restrict__ out) {
  const int b = blockIdx.x;
  const int j = threadIdx.x;
  const int o = j & 63;
  const int s = j >> 6;

  __shared__ float red[2][8][64];  // [buf][slice][o], double-buffered

  // ---- pin weights in registers ----
  float win[kF];
#pragma unroll
  for (int q = 0; q < 16; ++q) {
    const float4 v = *reinterpret_cast<const float4*>(W_in + j * kF + q * 4);
    win[q * 4 + 0] = v.x; win[q * 4 + 1] = v.y;
    win[q * 4 + 2] = v.z; win[q * 4 + 3] = v.w;
  }
  float wout[64];
#pragma unroll
  for (int q = 0; q < 16; ++q) {
    const float4 v =
        *reinterpret_cast<const float4*>(W_out + o * kH + s * 64 + q * 4);
    wout[q * 4 + 0] = v.x; wout[q * 4 + 1] = v.y;
    wout[q * 4 + 2] = v.z; wout[q * 4 + 3] = v.w;
  }
  const float bin_j = b_in[j];
  const float bout_o = b_out[o];

  // ---- carried state (registers only) ----
  float mem1 = 0.0f, rst1 = 0.0f;
  float memo = 0.0f, rsto = 0.0f;
  unsigned long long mask = 0ull;  // this wave's spikes from layer1(t-1)

  const float* xrow = x + (size_t)b * kT * kF;
  float* out_mem = out + (size_t)b * kT * kO + o;
  float* out_spk = out_mem + (size_t)kB * kT * kO;

  f32x16 sx0, sx1, sx2, sx3;  // x_t in SGPRs (wave-uniform)

#define ISSUE_X(tt)                                                        \
  do {                                                                     \
    const float* xp = xrow + (size_t)(tt) * kF;                            \
    asm volatile("s_load_dwordx16 %0, %4, 0x0\n\t"                         \
                 "s_load_dwordx16 %1, %4, 0x40\n\t"                        \
                 "s_load_dwordx16 %2, %4, 0x80\n\t"                        \
                 "s_load_dwordx16 %3, %4, 0xc0"                            \
                 : "=&s"(sx0), "=&s"(sx1), "=&s"(sx2), "=&s"(sx3)          \
                 : "s"(xp));                                               \
  } while (0)

  // barrier WITHOUT vmcnt drain: only lgkm (ds_write + s_loads) must land.
#define BARRIER() asm volatile("s_waitcnt lgkmcnt(0)\n\ts_barrier" ::: "memory")

  // re-establish data dependency: layer-1 consumers of sx* may not be
  // scheduled above the barrier's drain (rule-18 analog).
#define PIN_X()                                                            \
  asm volatile("s_waitcnt lgkmcnt(0)"                                      \
               : "+s"(sx0), "+s"(sx1), "+s"(sx2), "+s"(sx3)::"memory")

#define LAYER1()                                                           \
  do {                                                                     \
    float c0 = bin_j, c1 = 0.0f, c2 = 0.0f, c3 = 0.0f;                     \
    _Pragma("unroll") for (int q = 0; q < 16; ++q) {                       \
      c0 = fmaf(XV(4 * q + 0), win[4 * q + 0], c0);                        \
      c1 = fmaf(XV(4 * q + 1), win[4 * q + 1], c1);                        \
      c2 = fmaf(XV(4 * q + 2), win[4 * q + 2], c2);                        \
      c3 = fmaf(XV(4 * q + 3), win[4 * q + 3], c3);                        \
    }                                                                      \
    const float cur1 = (c0 + c1) + (c2 + c3);                              \
    mem1 = kBeta * mem1 + cur1 - rst1;                                     \
    const bool p = mem1 > kThresh;                                         \
    mask = __ballot(p);                                                    \
    rst1 = p ? 1.0f : 0.0f;                                                \
  } while (0)

#define LAYER2(buf)                                                        \
  do {                                                                     \
    const unsigned mlo = (unsigned)mask;                                   \
    const unsigned mhi = (unsigned)(mask >> 32);                           \
    float a0 = 0.0f, a1 = 0.0f, a2 = 0.0f, a3 = 0.0f;                      \
    _Pragma("unroll") for (int q = 0; q < 16; ++q) {                       \
      a0 = fmaf(BITF(4 * q + 0), wout[4 * q + 0], a0);                     \
      a1 = fmaf(BITF(4 * q + 1), wout[4 * q + 1], a1);                     \
      a2 = fmaf(BITF(4 * q + 2), wout[4 * q + 2], a2);                     \
      a3 = fmaf(BITF(4 * q + 3), wout[4 * q + 3], a3);                     \
    }                                                                      \
    red[(buf)][s][o] = (a0 + a1) + (a2 + a3);                              \
  } while (0)

  // ---- prologue: step 0 layer-1 ----
  ISSUE_X(0);
  BARRIER();
  PIN_X();
  LAYER1();  // -> mask for step 0

  // ---- main loop: iteration t does layer2/reduce(t-1) + layer1(t) ----
  for (int t = 1; t < kT; ++t) {
    ISSUE_X(t);
    LAYER2((t - 1) & 1);   // uses mask from layer1(t-1); ds_write red
    BARRIER();             // red visible; x_t drained
    PIN_X();

    // reduce(t-1): all waves redundantly (consistent), wave 0 stores.
    {
      const int buf = (t - 1) & 1;
      float co = bout_o;
#pragma unroll
      for (int s2 = 0; s2 < 8; ++s2) co += red[buf][s2][o];
      memo = kBeta * memo + co - rsto;
      const float so = (memo > kThresh) ? 1.0f : 0.0f;
      rsto = so;
      if (j < kO) {
        out_mem[(t - 1) * kO] = memo;
        out_spk[(t - 1) * kO] = so;
      }
    }

    LAYER1();  // -> mask for step t (interleaves with reduce latency)
  }

  // ---- epilogue: layer2/reduce for step T-1 ----
  LAYER2((kT - 1) & 1);
  BARRIER();
  {
    const int buf = (kT - 1) & 1;
    float co = bout_o;
#pragma unroll
    for (int s2 = 0; s2 < 8; ++s2) co += red[buf][s2][o];
    memo = kBeta * memo + co - rsto;
    const float so = (memo > kThresh) ? 1.0f : 0.0f;
    if (j < kO) {
      out_mem[(kT - 1) * kO] = memo;
      out_spk[(kT - 1) * kO] = so;
    }
  }

#undef ISSUE_X
#undef BARRIER
#undef PIN_X
#undef LAYER1
#undef LAYER2
}

extern "C" void kernel_launch(void* const* d_in, const int* in_sizes, int n_in,
                              void* d_out, int out_size, void* d_ws,
                              size_t ws_size, hipStream_t stream) {
  const float* x = (const float*)d_in[0];
  const float* W_in = (const float*)d_in[1];
  const float* b_in = (const float*)d_in[2];
  const float* W_out = (const float*)d_in[3];
  const float* b_out = (const float*)d_in[4];
  float* out = (float*)d_out;

  hipLaunchKernelGGL(snn_fused2, dim3(kB), dim3(kThreads), 0, stream,
                     x, W_in, b_in, W_out, b_out, out);
}